// Round 1
// baseline (376.827 us; speedup 1.0000x reference)
//
#include <hip/hip_runtime.h>
#include <stdint.h>

typedef unsigned int uint;
typedef unsigned short ushort;
typedef __attribute__((ext_vector_type(4))) float  f32x4;
typedef __attribute__((ext_vector_type(8))) __bf16 bf16x8;

#define SCALE 0.125f   // 1/sqrt(64)

__device__ __forceinline__ ushort f2bf(float f) {
  uint u = __builtin_bit_cast(uint, f);
  u += 0x7FFFu + ((u >> 16) & 1u);
  return (ushort)(u >> 16);
}
__device__ __forceinline__ uint pack2bf(float a, float b) {
  return (uint)f2bf(a) | ((uint)f2bf(b) << 16);
}
__device__ __forceinline__ float bflo(uint u) { return __builtin_bit_cast(float, u << 16); }
__device__ __forceinline__ float bfhi(uint u) { return __builtin_bit_cast(float, u & 0xFFFF0000u); }

__device__ __forceinline__ void gload_lds16(const void* g, void* l) {
  __builtin_amdgcn_global_load_lds((const __attribute__((address_space(1))) void*)g,
                                   (__attribute__((address_space(3))) void*)l, 16, 0, 0);
}

// ---------------- conversions ----------------

__global__ void cvt_x_kernel(const float4* __restrict__ in, uint2* __restrict__ out) {
  int i = blockIdx.x * blockDim.x + threadIdx.x;   // 524288 threads
  #pragma unroll
  for (int k = 0; k < 8; ++k) {
    int idx = i + k * 524288;                       // total 4194304 float4s
    float4 f = in[idx];
    out[idx] = make_uint2(pack2bf(f.x, f.y), pack2bf(f.z, f.w));
  }
}

// Wq/Wk/Wv [1024][1024] f32 -> WqkvT [3072][1024] bf16 (transposed: row=out col, k contiguous)
__global__ __launch_bounds__(256) void cvt_wqkv_kernel(
    const float* __restrict__ Wq, const float* __restrict__ Wk, const float* __restrict__ Wv,
    ushort* __restrict__ WT) {
  __shared__ float tile[32][33];
  int mat = blockIdx.z;
  const float* W = (mat == 0) ? Wq : (mat == 1) ? Wk : Wv;
  int tx = threadIdx.x & 31, ty = threadIdx.x >> 5;
  int c0 = blockIdx.x * 32, r0 = blockIdx.y * 32;
  #pragma unroll
  for (int i = 0; i < 4; ++i)
    tile[ty + i*8][tx] = W[(size_t)(r0 + ty + i*8) * 1024 + c0 + tx];
  __syncthreads();
  #pragma unroll
  for (int i = 0; i < 4; ++i)
    WT[(size_t)(mat*1024 + c0 + ty + i*8) * 1024 + r0 + tx] = f2bf(tile[tx][ty + i*8]);
}

// ---------------- bf16 GEMM, m97-style 128x128 tile ----------------
// C[M,N] = A[M,K] @ B^T  (B stored [N][K]).  CT = ushort(bf16) or float.
template<typename CT>
__global__ __launch_bounds__(256, 2) void gemm_bt(
    const ushort* __restrict__ A, const ushort* __restrict__ B, CT* __restrict__ C,
    int K, int ldc,
    const float* __restrict__ bias0, const float* __restrict__ bias1, const float* __restrict__ bias2,
    int b_batch_stride) {
  __shared__ ushort As[128 * 64];
  __shared__ ushort Bs[128 * 64];
  const int t = threadIdx.x;
  const int w = t >> 6, l = t & 63;
  const int wr = w >> 1, wc = w & 1;
  const int m0 = blockIdx.y * 128;
  const int n0 = blockIdx.x * 128;
  const ushort* Ap = A + (size_t)m0 * K;
  const ushort* Bp = B + (size_t)(m0 >> 12) * b_batch_stride + (size_t)n0 * K;

  f32x4 acc[4][4];
  const f32x4 zf = {0.f, 0.f, 0.f, 0.f};
  #pragma unroll
  for (int i = 0; i < 4; ++i)
    #pragma unroll
    for (int j = 0; j < 4; ++j) acc[i][j] = zf;

  const int lr = l & 15, lg = l >> 4;

  for (int kt = 0; kt < K; kt += 64) {
    #pragma unroll
    for (int i = 0; i < 4; ++i) {
      int gb = w * 64 + i * 256;           // wave-uniform granule base
      int g  = gb + l;                     // per-lane granule
      int row = g >> 3, c16 = g & 7;
      gload_lds16(Ap + (size_t)row * K + kt + c16 * 8, (void*)(As + gb * 8));
      gload_lds16(Bp + (size_t)row * K + kt + c16 * 8, (void*)(Bs + gb * 8));
    }
    __syncthreads();
    #pragma unroll
    for (int kk = 0; kk < 64; kk += 32) {
      bf16x8 a[4], b[4];
      #pragma unroll
      for (int m = 0; m < 4; ++m)
        a[m] = *(const bf16x8*)(As + (wr*64 + m*16 + lr) * 64 + kk + lg * 8);
      #pragma unroll
      for (int n = 0; n < 4; ++n)
        b[n] = *(const bf16x8*)(Bs + (wc*64 + n*16 + lr) * 64 + kk + lg * 8);
      #pragma unroll
      for (int m = 0; m < 4; ++m)
        #pragma unroll
        for (int n = 0; n < 4; ++n)
          acc[m][n] = __builtin_amdgcn_mfma_f32_16x16x32_bf16(a[m], b[n], acc[m][n], 0, 0, 0);
    }
    __syncthreads();
  }

  const float* bp = (n0 < 1024) ? bias0 : (n0 < 2048) ? bias1 : bias2;
  #pragma unroll
  for (int n = 0; n < 4; ++n) {
    int col = n0 + wc*64 + n*16 + lr;
    float bv = bp[col & 1023];
    #pragma unroll
    for (int m = 0; m < 4; ++m) {
      #pragma unroll
      for (int j = 0; j < 4; ++j) {
        int row = m0 + wr*64 + m*16 + lg*4 + j;   // C/D: col=lane&15, row=(lane>>4)*4+j (m89)
        float v = acc[m][n][j] + bv;
        if constexpr (sizeof(CT) == 2) C[(size_t)row * ldc + col] = (CT)f2bf(v);
        else                           C[(size_t)row * ldc + col] = v;
      }
    }
  }
}

// ---------------- feature-dim softmax (64-chunks), 4 lanes per chunk ----------------

__device__ __forceinline__ void unpack8(uint4 u, float s, float* x) {
  x[0]=bflo(u.x)*s; x[1]=bfhi(u.x)*s; x[2]=bflo(u.y)*s; x[3]=bfhi(u.y)*s;
  x[4]=bflo(u.z)*s; x[5]=bfhi(u.z)*s; x[6]=bflo(u.w)*s; x[7]=bfhi(u.w)*s;
}

__device__ __forceinline__ void softmax16(float* x) {
  float m = x[0];
  #pragma unroll
  for (int i = 1; i < 16; ++i) m = fmaxf(m, x[i]);
  m = fmaxf(m, __shfl_xor(m, 1));
  m = fmaxf(m, __shfl_xor(m, 2));
  float s = 0.f;
  #pragma unroll
  for (int i = 0; i < 16; ++i) { x[i] = __expf(x[i] - m); s += x[i]; }
  s += __shfl_xor(s, 1);
  s += __shfl_xor(s, 2);
  float inv = 1.f / s;
  #pragma unroll
  for (int i = 0; i < 16; ++i) x[i] *= inv;
}

__global__ __launch_bounds__(256) void softmax_qkm_kernel(
    const ushort* __restrict__ QKV, const float* __restrict__ mk,
    ushort* __restrict__ qs, ushort* __restrict__ wbuf) {
  int bid = blockIdx.x;
  bool kmode = bid >= 4096;
  int cb = kmode ? bid - 4096 : bid;
  int t = threadIdx.x;
  int cid = cb * 64 + (t >> 2);       // chunk id 0..262143
  int sub = t & 3;
  int row = cid >> 4, h = cid & 15;
  int col0 = h * 64 + sub * 16;

  if (!kmode) {
    const uint4* p = (const uint4*)(QKV + (size_t)row * 3072 + col0);
    float x[16];
    unpack8(p[0], SCALE, x);
    unpack8(p[1], SCALE, x + 8);
    softmax16(x);
    uint4 o0 = make_uint4(pack2bf(x[0],x[1]), pack2bf(x[2],x[3]), pack2bf(x[4],x[5]), pack2bf(x[6],x[7]));
    uint4 o1 = make_uint4(pack2bf(x[8],x[9]), pack2bf(x[10],x[11]), pack2bf(x[12],x[13]), pack2bf(x[14],x[15]));
    uint4* q = (uint4*)(qs + (size_t)row * 1024 + col0);
    q[0] = o0; q[1] = o1;
  } else {
    const uint4* p = (const uint4*)(QKV + (size_t)row * 3072 + 1024 + col0);
    float ks[16];
    unpack8(p[0], SCALE, ks);
    unpack8(p[1], SCALE, ks + 8);
    softmax16(ks);
    const float4* mp = (const float4*)(mk + (size_t)row * 1024 + col0);
    float ms[16];
    #pragma unroll
    for (int i = 0; i < 4; ++i) {
      float4 f = mp[i];
      ms[i*4+0] = f.x * SCALE; ms[i*4+1] = f.y * SCALE;
      ms[i*4+2] = f.z * SCALE; ms[i*4+3] = f.w * SCALE;
    }
    softmax16(ms);
    #pragma unroll
    for (int i = 0; i < 16; ++i) ks[i] += ms[i];
    uint4 o0 = make_uint4(pack2bf(ks[0],ks[1]), pack2bf(ks[2],ks[3]), pack2bf(ks[4],ks[5]), pack2bf(ks[6],ks[7]));
    uint4 o1 = make_uint4(pack2bf(ks[8],ks[9]), pack2bf(ks[10],ks[11]), pack2bf(ks[12],ks[13]), pack2bf(ks[14],ks[15]));
    uint4* q = (uint4*)(wbuf + (size_t)row * 1024 + col0);
    q[0] = o0; q[1] = o1;
  }
}

// ---------------- S[b,h] = (k_soft+m_soft)^T v : split-K outer-product + atomics ----------------

__global__ __launch_bounds__(256) void kv_accum_kernel(
    const ushort* __restrict__ wbuf, const ushort* __restrict__ QKV, float* __restrict__ S) {
  __shared__ ushort Ws[128 * 64];
  __shared__ ushort Vs[128 * 64];
  int bx = blockIdx.x;
  int bh = bx >> 5, nc = bx & 31;
  int b = bh >> 4, h = bh & 15;
  int row0 = b * 4096 + nc * 128;
  int t = threadIdx.x, w = t >> 6, l = t & 63;
  #pragma unroll
  for (int i = 0; i < 4; ++i) {
    int gb = w * 64 + i * 256, g = gb + l;
    int r = g >> 3, c16 = g & 7;
    gload_lds16(wbuf + (size_t)(row0 + r) * 1024 + h * 64 + c16 * 8, (void*)(Ws + gb * 8));
    gload_lds16(QKV  + (size_t)(row0 + r) * 3072 + 2048 + h * 64 + c16 * 8, (void*)(Vs + gb * 8));
  }
  __syncthreads();
  int d0 = (t & 15) * 4, e0 = (t >> 4) * 4;
  float acc[4][4] = {};
  #pragma unroll 4
  for (int n = 0; n < 128; ++n) {
    uint2 wp = *(const uint2*)(Ws + n * 64 + d0);
    uint2 vp = *(const uint2*)(Vs + n * 64 + e0);
    float wd[4] = { bflo(wp.x), bfhi(wp.x), bflo(wp.y), bfhi(wp.y) };
    float vd[4] = { bflo(vp.x), bfhi(vp.x), bflo(vp.y), bfhi(vp.y) };
    #pragma unroll
    for (int i = 0; i < 4; ++i)
      #pragma unroll
      for (int j = 0; j < 4; ++j) acc[i][j] += wd[i] * vd[j];
  }
  float* Sp = S + (size_t)bh * 4096;
  #pragma unroll
  for (int i = 0; i < 4; ++i)
    #pragma unroll
    for (int j = 0; j < 4; ++j)
      atomicAdd(Sp + (d0 + i) * 64 + e0 + j, acc[i][j]);
}

// ---------------- W2T[b][o][i] = sum_e S[b,h(i)][i%64][e] * Wo[h*64+e][o]  (bf16, BT layout) ----

__global__ __launch_bounds__(256) void make_w2t_kernel(
    const float* __restrict__ S, const float* __restrict__ Wo, ushort* __restrict__ W2T) {
  int bx = blockIdx.x;            // 1024 = b(4) h(16) ot(4) it(4)
  int b = bx >> 8, h = (bx >> 4) & 15, ot = (bx >> 2) & 3, it = bx & 3;
  int t = threadIdx.x;
  __shared__ float Ss[16 * 64];
  const float* Sp = S + (size_t)(b * 16 + h) * 4096 + it * 1024;
  #pragma unroll
  for (int i = 0; i < 4; ++i) Ss[t + i * 256] = Sp[t + i * 256];
  __syncthreads();
  int o = ot * 256 + t;
  float acc[16] = {};
  for (int e = 0; e < 64; ++e) {
    float wo = Wo[(size_t)(h * 64 + e) * 1024 + o];
    #pragma unroll
    for (int i = 0; i < 16; ++i) acc[i] += Ss[i * 64 + e] * wo;
  }
  ushort* dst = W2T + (size_t)(b * 1024 + o) * 1024 + h * 64 + it * 16;
  #pragma unroll
  for (int i = 0; i < 16; ++i) dst[i] = f2bf(acc[i]);
}

// ---------------- launch ----------------

extern "C" void kernel_launch(void* const* d_in, const int* in_sizes, int n_in,
                              void* d_out, int out_size, void* d_ws, size_t ws_size,
                              hipStream_t stream) {
  const float* x  = (const float*)d_in[0];
  const float* mk = (const float*)d_in[1];
  const float* Wq = (const float*)d_in[2];
  const float* bq = (const float*)d_in[3];
  const float* Wk = (const float*)d_in[4];
  const float* bk = (const float*)d_in[5];
  const float* Wv = (const float*)d_in[6];
  const float* bv = (const float*)d_in[7];
  const float* Wo = (const float*)d_in[8];
  const float* bo = (const float*)d_in[9];
  float* out = (float*)d_out;

  char* ws = (char*)d_ws;
  ushort* xb    = (ushort*)(ws);                    //  33,554,432
  ushort* wqkvT = (ushort*)(ws +  33554432);        //   6,291,456
  ushort* QKV   = (ushort*)(ws +  39845888);        // 100,663,296
  ushort* qs    = (ushort*)(ws + 140509184);        //  33,554,432
  ushort* wbuf  = (ushort*)(ws + 174063616);        //  33,554,432
  float*  S     = (float* )(ws + 207618048);        //   1,048,576
  ushort* W2T   = (ushort*)(ws + 208666624);        //   8,388,608

  cvt_x_kernel<<<2048, 256, 0, stream>>>((const float4*)x, (uint2*)xb);
  cvt_wqkv_kernel<<<dim3(32, 32, 3), 256, 0, stream>>>(Wq, Wk, Wv, wqkvT);
  gemm_bt<ushort><<<dim3(24, 128), 256, 0, stream>>>(xb, wqkvT, QKV, 1024, 3072, bq, bk, bv, 0);
  softmax_qkm_kernel<<<8192, 256, 0, stream>>>(QKV, mk, qs, wbuf);
  hipMemsetAsync(S, 0, 64 * 4096 * sizeof(float), stream);
  kv_accum_kernel<<<2048, 256, 0, stream>>>(wbuf, QKV, S);
  make_w2t_kernel<<<1024, 256, 0, stream>>>(S, Wo, W2T);
  gemm_bt<float><<<dim3(8, 128), 256, 0, stream>>>(qs, W2T, out, 1024, 1024, bo, bo, bo, 1024 * 1024);
}

// Round 2
// 362.518 us; speedup vs baseline: 1.0395x; 1.0395x over previous
//
#include <hip/hip_runtime.h>
#include <stdint.h>

typedef unsigned int uint;
typedef unsigned short ushort;
typedef __attribute__((ext_vector_type(4))) float  f32x4;
typedef __attribute__((ext_vector_type(8))) __bf16 bf16x8;

#define SCALE 0.125f   // 1/sqrt(64)

__device__ __forceinline__ ushort f2bf(float f) {
  uint u = __builtin_bit_cast(uint, f);
  u += 0x7FFFu + ((u >> 16) & 1u);
  return (ushort)(u >> 16);
}
__device__ __forceinline__ uint pack2bf(float a, float b) {
  return (uint)f2bf(a) | ((uint)f2bf(b) << 16);
}
__device__ __forceinline__ float bflo(uint u) { return __builtin_bit_cast(float, u << 16); }
__device__ __forceinline__ float bfhi(uint u) { return __builtin_bit_cast(float, u & 0xFFFF0000u); }

__device__ __forceinline__ void gload_lds16(const void* g, void* l) {
  __builtin_amdgcn_global_load_lds((const __attribute__((address_space(1))) void*)g,
                                   (__attribute__((address_space(3))) void*)l, 16, 0, 0);
}

// ---------------- conversions ----------------

__global__ void cvt_x_kernel(const float4* __restrict__ in, uint2* __restrict__ out) {
  int i = blockIdx.x * blockDim.x + threadIdx.x;   // 524288 threads
  #pragma unroll
  for (int k = 0; k < 8; ++k) {
    int idx = i + k * 524288;                       // total 4194304 float4s
    float4 f = in[idx];
    out[idx] = make_uint2(pack2bf(f.x, f.y), pack2bf(f.z, f.w));
  }
}

// Wq/Wk/Wv [1024][1024] f32 -> WqkvT [3072][1024] bf16 (transposed: row=out col, k contiguous)
__global__ __launch_bounds__(256) void cvt_wqkv_kernel(
    const float* __restrict__ Wq, const float* __restrict__ Wk, const float* __restrict__ Wv,
    ushort* __restrict__ WT) {
  __shared__ float tile[32][33];
  int mat = blockIdx.z;
  const float* W = (mat == 0) ? Wq : (mat == 1) ? Wk : Wv;
  int tx = threadIdx.x & 31, ty = threadIdx.x >> 5;
  int c0 = blockIdx.x * 32, r0 = blockIdx.y * 32;
  #pragma unroll
  for (int i = 0; i < 4; ++i)
    tile[ty + i*8][tx] = W[(size_t)(r0 + ty + i*8) * 1024 + c0 + tx];
  __syncthreads();
  #pragma unroll
  for (int i = 0; i < 4; ++i)
    WT[(size_t)(mat*1024 + c0 + ty + i*8) * 1024 + r0 + tx] = f2bf(tile[tx][ty + i*8]);
}

// ---------------- bf16 GEMM, 256x256 tile, BK=64, 8-phase counted-vmcnt schedule ----------------
// C[M,N] = A[M,K] @ B^T  (B stored [N][K]).  CT = ushort(bf16) or float.
// LDS 128 KiB dynamic: buf[2] x { A[256][64] , B[256][64] } bf16, XOR-swizzled (col ^= (row&7)<<3).
// Per K-tile (4 phases): phase q computes m-stripe {2q,2q+1} x all n x kk{0,32} = 16 MFMA.
// B frags read once at q0 (freeing B region), A stripe-by-stripe. Staging (1 half-tile/phase):
//   q0: Ah1(s+1) | q1: Bh0(s+2) | q2: Bh1(s+2) | q3: Ah0(s+2)   -> 3 half-tiles in flight => vmcnt(6).
template<typename CT>
__global__ __launch_bounds__(512, 2) void gemm256(
    const ushort* __restrict__ A, const ushort* __restrict__ B, CT* __restrict__ C,
    int K, int ldc,
    const float* __restrict__ bias0, const float* __restrict__ bias1, const float* __restrict__ bias2,
    int b_batch_stride, int nbx) {
  extern __shared__ ushort smem[];   // 131072 bytes
  const int t = threadIdx.x;
  const int wid = t >> 6, l = t & 63;
  const int wr = wid >> 2, wc = wid & 3;
  const int lr = l & 15, lg = l >> 4;

  // XCD-bijective block swizzle (grid % 8 == 0 for both GEMMs)
  const int cpx = gridDim.x >> 3;
  const int bid = blockIdx.x;
  const int swz = (bid & 7) * cpx + (bid >> 3);
  const int m0 = (swz / nbx) * 256;
  const int n0 = (swz % nbx) * 256;

  const ushort* Ap = A + (size_t)m0 * K;
  const ushort* Bp = B + (size_t)(m0 >> 12) * b_batch_stride + (size_t)n0 * K;
  const int nt = K >> 6;

  // staging geometry: per instruction, 512 threads x 16B = 64 rows of a [128][64] half
  const int srow = (wid << 3) + (l >> 3);            // 0..63
  const int scol = ((l & 7) ^ (l >> 3)) * 8;         // pre-inverse-swizzled source col
  // STAGE(mat,h,u): mat 0=A 1=B, half h, K-tile u
#define STAGE(mat, h, u, Ptr) do { \
    const ushort* g0 = (Ptr) + (size_t)((h)*128 + srow) * K + (u)*64 + scol; \
    const ushort* g1 = (Ptr) + (size_t)((h)*128 + 64 + srow) * K + (u)*64 + scol; \
    ushort* ld = smem + ((u)&1)*32768 + (mat)*16384 + (h)*8192 + wid*512; \
    gload_lds16(g0, (void*)ld); \
    gload_lds16(g1, (void*)(ld + 4096)); \
  } while (0)

  f32x4 acc[8][4];
  const f32x4 zf = {0.f, 0.f, 0.f, 0.f};
  #pragma unroll
  for (int i = 0; i < 8; ++i)
    #pragma unroll
    for (int j = 0; j < 4; ++j) acc[i][j] = zf;

  // prologue: tile0 fully, tile1 {Bh0,Bh1,Ah0}; tile0 landed after vmcnt(6)
  STAGE(1, 0, 0, Bp); STAGE(1, 1, 0, Bp); STAGE(0, 0, 0, Ap); STAGE(0, 1, 0, Ap);
  if (nt > 1) { STAGE(1, 0, 1, Bp); STAGE(1, 1, 1, Bp); STAGE(0, 0, 1, Ap); }
  asm volatile("s_waitcnt vmcnt(6)" ::: "memory");
  __builtin_amdgcn_s_barrier();

  bf16x8 bfr[4][2];
  for (int s = 0; s < nt; ++s) {
    const ushort* Asb = smem + (s & 1) * 32768;
    const ushort* Bsb = Asb + 16384;
    #pragma unroll
    for (int q = 0; q < 4; ++q) {
      bf16x8 afr[2][2];
      if (q == 0) {
        #pragma unroll
        for (int n = 0; n < 4; ++n)
          #pragma unroll
          for (int kk = 0; kk < 2; ++kk) {
            int row = wc * 64 + n * 16 + lr;
            bfr[n][kk] = *(const bf16x8*)(Bsb + row * 64 + ((kk * 32 + lg * 8) ^ ((lr & 7) << 3)));
          }
      }
      #pragma unroll
      for (int mi = 0; mi < 2; ++mi)
        #pragma unroll
        for (int kk = 0; kk < 2; ++kk) {
          int row = wr * 128 + (q * 2 + mi) * 16 + lr;
          afr[mi][kk] = *(const bf16x8*)(Asb + row * 64 + ((kk * 32 + lg * 8) ^ ((lr & 7) << 3)));
        }
      // stage exactly one half-tile per phase (region freed by the schedule above)
      if (q == 0)      { if (s + 1 < nt) STAGE(0, 1, s + 1, Ap); }
      else if (q == 1) { if (s + 2 < nt) STAGE(1, 0, s + 2, Bp); }
      else if (q == 2) { if (s + 2 < nt) STAGE(1, 1, s + 2, Bp); }
      else             { if (s + 2 < nt) STAGE(0, 0, s + 2, Ap); }
      __builtin_amdgcn_s_barrier();
      asm volatile("s_waitcnt lgkmcnt(0)" ::: "memory");
      __builtin_amdgcn_sched_barrier(0);
      __builtin_amdgcn_s_setprio(1);
      #pragma unroll
      for (int mi = 0; mi < 2; ++mi)
        #pragma unroll
        for (int n = 0; n < 4; ++n)
          #pragma unroll
          for (int kk = 0; kk < 2; ++kk)
            acc[q * 2 + mi][n] = __builtin_amdgcn_mfma_f32_16x16x32_bf16(
                afr[mi][kk], bfr[n][kk], acc[q * 2 + mi][n], 0, 0, 0);
      __builtin_amdgcn_s_setprio(0);
      if (q == 3) {
        if (s + 2 < nt)      { asm volatile("s_waitcnt vmcnt(6)" ::: "memory"); }
        else if (s + 1 < nt) { asm volatile("s_waitcnt vmcnt(0)" ::: "memory"); }
      }
      __builtin_amdgcn_s_barrier();
    }
  }
#undef STAGE

  // epilogue: C/D mapping col=lane&15, row=(lane>>4)*4+j (m89)
  #pragma unroll
  for (int n = 0; n < 4; ++n) {
    int col = n0 + wc * 64 + n * 16 + lr;
    const float* bp = (col < 1024) ? bias0 : (col < 2048) ? bias1 : bias2;
    float bv = bp[col & 1023];
    #pragma unroll
    for (int m = 0; m < 8; ++m) {
      #pragma unroll
      for (int j = 0; j < 4; ++j) {
        int row = m0 + wr * 128 + m * 16 + lg * 4 + j;
        float v = acc[m][n][j] + bv;
        if constexpr (sizeof(CT) == 2) C[(size_t)row * ldc + col] = (CT)f2bf(v);
        else                           C[(size_t)row * ldc + col] = v;
      }
    }
  }
}

// ---------------- feature-dim softmax (64-chunks), 4 lanes per chunk ----------------

__device__ __forceinline__ void unpack8(uint4 u, float s, float* x) {
  x[0]=bflo(u.x)*s; x[1]=bfhi(u.x)*s; x[2]=bflo(u.y)*s; x[3]=bfhi(u.y)*s;
  x[4]=bflo(u.z)*s; x[5]=bfhi(u.z)*s; x[6]=bflo(u.w)*s; x[7]=bfhi(u.w)*s;
}

__device__ __forceinline__ void softmax16(float* x) {
  float m = x[0];
  #pragma unroll
  for (int i = 1; i < 16; ++i) m = fmaxf(m, x[i]);
  m = fmaxf(m, __shfl_xor(m, 1));
  m = fmaxf(m, __shfl_xor(m, 2));
  float s = 0.f;
  #pragma unroll
  for (int i = 0; i < 16; ++i) { x[i] = __expf(x[i] - m); s += x[i]; }
  s += __shfl_xor(s, 1);
  s += __shfl_xor(s, 2);
  float inv = 1.f / s;
  #pragma unroll
  for (int i = 0; i < 16; ++i) x[i] *= inv;
}

__global__ __launch_bounds__(256) void softmax_qkm_kernel(
    const ushort* __restrict__ QKV, const float* __restrict__ mk,
    ushort* __restrict__ qs, ushort* __restrict__ wbuf) {
  int bid = blockIdx.x;
  bool kmode = bid >= 4096;
  int cb = kmode ? bid - 4096 : bid;
  int t = threadIdx.x;
  int cid = cb * 64 + (t >> 2);       // chunk id 0..262143
  int sub = t & 3;
  int row = cid >> 4, h = cid & 15;
  int col0 = h * 64 + sub * 16;

  if (!kmode) {
    const uint4* p = (const uint4*)(QKV + (size_t)row * 3072 + col0);
    float x[16];
    unpack8(p[0], SCALE, x);
    unpack8(p[1], SCALE, x + 8);
    softmax16(x);
    uint4 o0 = make_uint4(pack2bf(x[0],x[1]), pack2bf(x[2],x[3]), pack2bf(x[4],x[5]), pack2bf(x[6],x[7]));
    uint4 o1 = make_uint4(pack2bf(x[8],x[9]), pack2bf(x[10],x[11]), pack2bf(x[12],x[13]), pack2bf(x[14],x[15]));
    uint4* q = (uint4*)(qs + (size_t)row * 1024 + col0);
    q[0] = o0; q[1] = o1;
  } else {
    const uint4* p = (const uint4*)(QKV + (size_t)row * 3072 + 1024 + col0);
    float ks[16];
    unpack8(p[0], SCALE, ks);
    unpack8(p[1], SCALE, ks + 8);
    softmax16(ks);
    const float4* mp = (const float4*)(mk + (size_t)row * 1024 + col0);
    float ms[16];
    #pragma unroll
    for (int i = 0; i < 4; ++i) {
      float4 f = mp[i];
      ms[i*4+0] = f.x * SCALE; ms[i*4+1] = f.y * SCALE;
      ms[i*4+2] = f.z * SCALE; ms[i*4+3] = f.w * SCALE;
    }
    softmax16(ms);
    #pragma unroll
    for (int i = 0; i < 16; ++i) ks[i] += ms[i];
    uint4 o0 = make_uint4(pack2bf(ks[0],ks[1]), pack2bf(ks[2],ks[3]), pack2bf(ks[4],ks[5]), pack2bf(ks[6],ks[7]));
    uint4 o1 = make_uint4(pack2bf(ks[8],ks[9]), pack2bf(ks[10],ks[11]), pack2bf(ks[12],ks[13]), pack2bf(ks[14],ks[15]));
    uint4* q = (uint4*)(wbuf + (size_t)row * 1024 + col0);
    q[0] = o0; q[1] = o1;
  }
}

// ---------------- S[b,h] = (k_soft+m_soft)^T v : split-K outer-product + atomics ----------------

__global__ __launch_bounds__(256) void kv_accum_kernel(
    const ushort* __restrict__ wbuf, const ushort* __restrict__ QKV, float* __restrict__ S) {
  __shared__ ushort Ws[128 * 64];
  __shared__ ushort Vs[128 * 64];
  int bx = blockIdx.x;
  int bh = bx >> 5, nc = bx & 31;
  int b = bh >> 4, h = bh & 15;
  int row0 = b * 4096 + nc * 128;
  int t = threadIdx.x, w = t >> 6, l = t & 63;
  #pragma unroll
  for (int i = 0; i < 4; ++i) {
    int gb = w * 64 + i * 256, g = gb + l;
    int r = g >> 3, c16 = g & 7;
    gload_lds16(wbuf + (size_t)(row0 + r) * 1024 + h * 64 + c16 * 8, (void*)(Ws + gb * 8));
    gload_lds16(QKV  + (size_t)(row0 + r) * 3072 + 2048 + h * 64 + c16 * 8, (void*)(Vs + gb * 8));
  }
  __syncthreads();
  int d0 = (t & 15) * 4, e0 = (t >> 4) * 4;
  float acc[4][4] = {};
  #pragma unroll 4
  for (int n = 0; n < 128; ++n) {
    uint2 wp = *(const uint2*)(Ws + n * 64 + d0);
    uint2 vp = *(const uint2*)(Vs + n * 64 + e0);
    float wd[4] = { bflo(wp.x), bfhi(wp.x), bflo(wp.y), bfhi(wp.y) };
    float vd[4] = { bflo(vp.x), bfhi(vp.x), bflo(vp.y), bfhi(vp.y) };
    #pragma unroll
    for (int i = 0; i < 4; ++i)
      #pragma unroll
      for (int j = 0; j < 4; ++j) acc[i][j] += wd[i] * vd[j];
  }
  float* Sp = S + (size_t)bh * 4096;
  #pragma unroll
  for (int i = 0; i < 4; ++i)
    #pragma unroll
    for (int j = 0; j < 4; ++j)
      atomicAdd(Sp + (d0 + i) * 64 + e0 + j, acc[i][j]);
}

// ---------------- W2T[b][o][i] = sum_e S[b,h(i)][i%64][e] * Wo[h*64+e][o]  (bf16, BT layout) ----

__global__ __launch_bounds__(256) void make_w2t_kernel(
    const float* __restrict__ S, const float* __restrict__ Wo, ushort* __restrict__ W2T) {
  int bx = blockIdx.x;            // 1024 = b(4) h(16) ot(4) it(4)
  int b = bx >> 8, h = (bx >> 4) & 15, ot = (bx >> 2) & 3, it = bx & 3;
  int t = threadIdx.x;
  __shared__ float Ss[16 * 64];
  const float* Sp = S + (size_t)(b * 16 + h) * 4096 + it * 1024;
  #pragma unroll
  for (int i = 0; i < 4; ++i) Ss[t + i * 256] = Sp[t + i * 256];
  __syncthreads();
  int o = ot * 256 + t;
  float acc[16] = {};
  for (int e = 0; e < 64; ++e) {
    float wo = Wo[(size_t)(h * 64 + e) * 1024 + o];
    #pragma unroll
    for (int i = 0; i < 16; ++i) acc[i] += Ss[i * 64 + e] * wo;
  }
  ushort* dst = W2T + (size_t)(b * 1024 + o) * 1024 + h * 64 + it * 16;
  #pragma unroll
  for (int i = 0; i < 16; ++i) dst[i] = f2bf(acc[i]);
}

// ---------------- launch ----------------

extern "C" void kernel_launch(void* const* d_in, const int* in_sizes, int n_in,
                              void* d_out, int out_size, void* d_ws, size_t ws_size,
                              hipStream_t stream) {
  const float* x  = (const float*)d_in[0];
  const float* mk = (const float*)d_in[1];
  const float* Wq = (const float*)d_in[2];
  const float* bq = (const float*)d_in[3];
  const float* Wk = (const float*)d_in[4];
  const float* bk = (const float*)d_in[5];
  const float* Wv = (const float*)d_in[6];
  const float* bv = (const float*)d_in[7];
  const float* Wo = (const float*)d_in[8];
  const float* bo = (const float*)d_in[9];
  float* out = (float*)d_out;

  char* ws = (char*)d_ws;
  ushort* xb    = (ushort*)(ws);                    //  33,554,432
  ushort* wqkvT = (ushort*)(ws +  33554432);        //   6,291,456
  ushort* QKV   = (ushort*)(ws +  39845888);        // 100,663,296
  ushort* qs    = (ushort*)(ws + 140509184);        //  33,554,432
  ushort* wbuf  = (ushort*)(ws + 174063616);        //  33,554,432
  float*  S     = (float* )(ws + 207618048);        //   1,048,576
  ushort* W2T   = (ushort*)(ws + 208666624);        //   8,388,608

  hipFuncSetAttribute((const void*)gemm256<ushort>, hipFuncAttributeMaxDynamicSharedMemorySize, 131072);
  hipFuncSetAttribute((const void*)gemm256<float>,  hipFuncAttributeMaxDynamicSharedMemorySize, 131072);

  cvt_x_kernel<<<2048, 256, 0, stream>>>((const float4*)x, (uint2*)xb);
  cvt_wqkv_kernel<<<dim3(32, 32, 3), 256, 0, stream>>>(Wq, Wk, Wv, wqkvT);
  gemm256<ushort><<<768, 512, 131072, stream>>>(xb, wqkvT, QKV, 1024, 3072, bq, bk, bv, 0, 12);
  softmax_qkm_kernel<<<8192, 256, 0, stream>>>(QKV, mk, qs, wbuf);
  hipMemsetAsync(S, 0, 64 * 4096 * sizeof(float), stream);
  kv_accum_kernel<<<2048, 256, 0, stream>>>(wbuf, QKV, S);
  make_w2t_kernel<<<1024, 256, 0, stream>>>(S, Wo, W2T);
  gemm256<float><<<256, 512, 131072, stream>>>(qs, W2T, out, 1024, 1024, bo, bo, bo, 1024 * 1024, 4);
}